// Round 1
// baseline (1889.367 us; speedup 1.0000x reference)
//
#include <hip/hip_runtime.h>
#include <hip/hip_bf16.h>
#include <math.h>

#define V 32000
#define T 128
#define B 64
#define E 32
#define H 8
#define TB (T*B)   // 8192

// ---------------- params struct ----------------
struct P1 {
  const int* x; const float* emb;
  const float* Wf1; const float* bf1; const float* Wi1; const float* bi1;
  const float* WC1; const float* bC1; const float* Wo1; const float* bo1;
  const float* Wf2; const float* bf2; const float* Wi2; const float* bi2;
  const float* WC2; const float* bC2; const float* Wo2; const float* bo2;
};

__device__ __forceinline__ float sigm_f(float x) { return 1.f / (1.f + __expf(-x)); }
__device__ __forceinline__ float tanh_f(float x) { float e = __expf(2.f * x); return 1.f - 2.f / (e + 1.f); }

// ---------------- kernel 1: embed + e-part projections (bias folded in) ----------------
// pe layout: pe[(d*11 + g)*TB + r], g: 0=f,1=i,2=o,3..10=C[j];  r = t*B+b
__global__ __launch_bounds__(256) void k_embed(P1 p, float* __restrict__ pe) {
  int r = blockIdx.x * 256 + threadIdx.x;
  int idx = p.x[r];
  const float* e = p.emb + (long)idx * E;
  float ev[E];
  #pragma unroll
  for (int k = 0; k < E; k += 4) {
    float4 v4 = *(const float4*)(e + k);
    ev[k] = v4.x; ev[k+1] = v4.y; ev[k+2] = v4.z; ev[k+3] = v4.w;
  }
  #pragma unroll
  for (int d = 0; d < 2; ++d) {
    const float* Wf = d ? p.Wf2 : p.Wf1;
    const float* Wi = d ? p.Wi2 : p.Wi1;
    const float* Wo = d ? p.Wo2 : p.Wo1;
    const float* WC = d ? p.WC2 : p.WC1;
    const float* bC = d ? p.bC2 : p.bC1;
    float af = (d ? p.bf2 : p.bf1)[0];
    float ai = (d ? p.bi2 : p.bi1)[0];
    float ao = (d ? p.bo2 : p.bo1)[0];
    float ac[H];
    #pragma unroll
    for (int j = 0; j < H; ++j) ac[j] = bC[j];
    #pragma unroll
    for (int k = 0; k < E; ++k) {
      float ek = ev[k];
      af += ek * Wf[8 + k];
      ai += ek * Wi[8 + k];
      ao += ek * Wo[8 + k];
      #pragma unroll
      for (int j = 0; j < H; ++j) ac[j] += ek * WC[(8 + k) * H + j];
    }
    float* ped = pe + d * 11 * TB;
    ped[0 * TB + r] = af;
    ped[1 * TB + r] = ai;
    ped[2 * TB + r] = ao;
    #pragma unroll
    for (int j = 0; j < H; ++j) ped[(3 + j) * TB + r] = ac[j];
  }
}

// ---------------- kernel 2: sequential LSTM (one block per direction) ----------------
// hcat layout: hcat[r*16 + dir*8 + j]   (total_h, pre-update h recorded)
__global__ __launch_bounds__(64) void k_lstm(P1 p, const float* __restrict__ pe, float* __restrict__ hcat) {
  int dir = blockIdx.x;
  int lane = threadIdx.x;
  const float* Wf = dir ? p.Wf2 : p.Wf1;
  const float* Wi = dir ? p.Wi2 : p.Wi1;
  const float* Wo = dir ? p.Wo2 : p.Wo1;
  const float* WC = dir ? p.WC2 : p.WC1;
  float wf[8], wi[8], wo[8], wc[8][8];
  #pragma unroll
  for (int k = 0; k < 8; ++k) { wf[k] = Wf[k]; wi[k] = Wi[k]; wo[k] = Wo[k]; }
  #pragma unroll
  for (int k = 0; k < 8; ++k)
    #pragma unroll
    for (int j = 0; j < 8; ++j) wc[k][j] = WC[k * H + j];

  float h[8], C[8];
  #pragma unroll
  for (int j = 0; j < 8; ++j) { h[j] = 0.f; C[j] = 0.f; }

  const float* ped = pe + dir * 11 * TB;
  for (int s = 0; s < T; ++s) {
    int t = dir ? (T - 1 - s) : s;
    int r = t * B + lane;
    // record pre-update h (scan outputs carry-in h)
    float* hc = hcat + r * 16 + dir * 8;
    #pragma unroll
    for (int j = 0; j < 8; ++j) hc[j] = h[j];

    float af = ped[0 * TB + r];
    float ai = ped[1 * TB + r];
    float ao = ped[2 * TB + r];
    float ac[8];
    #pragma unroll
    for (int j = 0; j < 8; ++j) ac[j] = ped[(3 + j) * TB + r];
    #pragma unroll
    for (int k = 0; k < 8; ++k) {
      float hk = h[k];
      af += hk * wf[k];
      ai += hk * wi[k];
      ao += hk * wo[k];
      #pragma unroll
      for (int j = 0; j < 8; ++j) ac[j] += hk * wc[k][j];
    }
    float f = sigm_f(af), i = sigm_f(ai), o = sigm_f(ao);
    #pragma unroll
    for (int j = 0; j < 8; ++j) {
      float Cn = f * C[j] + i + tanh_f(ac[j]);
      C[j] = Cn;
      h[j] = o * tanh_f(Cn);
    }
  }
}

// ---------------- kernel 3: logits + log_softmax ----------------
#define R3 16        // rows per block
#define NT3 320      // threads (5 waves); 320*4 = 1280 cols per chunk
#define NW3 5
#define CH 25        // 32000 / 1280

__global__ __launch_bounds__(NT3) void k_out(const float* __restrict__ hcat,
                                             const float* __restrict__ Wout,
                                             const float* __restrict__ bout,
                                             float* __restrict__ out) {
  __shared__ float sTH[R3 * 16];
  __shared__ float sMS[NW3][R3][2];
  __shared__ float sZ[R3];
  int tid = threadIdx.x;
  int r0 = blockIdx.x * R3;
  if (tid < R3 * 16) sTH[tid] = hcat[r0 * 16 + tid];
  __syncthreads();

  float m[R3], sum[R3];
  #pragma unroll
  for (int q = 0; q < R3; ++q) { m[q] = -1e30f; sum[q] = 0.f; }

  // ---- pass A: online max/sumexp ----
  for (int c = 0; c < CH; ++c) {
    int v = c * (NT3 * 4) + tid * 4;
    float4 w[16];
    #pragma unroll
    for (int k = 0; k < 16; ++k) w[k] = *(const float4*)(Wout + k * V + v);
    float4 bb = *(const float4*)(bout + v);
    #pragma unroll
    for (int q = 0; q < R3; ++q) {
      const float4* th4 = (const float4*)(sTH + q * 16);
      float4 t0 = th4[0], t1 = th4[1], t2 = th4[2], t3 = th4[3];
      float th[16] = {t0.x,t0.y,t0.z,t0.w, t1.x,t1.y,t1.z,t1.w,
                      t2.x,t2.y,t2.z,t2.w, t3.x,t3.y,t3.z,t3.w};
      float lx = bb.x, ly = bb.y, lz = bb.z, lw = bb.w;
      #pragma unroll
      for (int k = 0; k < 16; ++k) {
        lx += th[k] * w[k].x; ly += th[k] * w[k].y;
        lz += th[k] * w[k].z; lw += th[k] * w[k].w;
      }
      float m4 = fmaxf(fmaxf(lx, ly), fmaxf(lz, lw));
      float mo = m[q];
      float mn = fmaxf(mo, m4);
      sum[q] = sum[q] * __expf(mo - mn)
             + __expf(lx - mn) + __expf(ly - mn) + __expf(lz - mn) + __expf(lw - mn);
      m[q] = mn;
    }
  }

  // ---- block reduce (m,s) per row ----
  int wave = tid >> 6, lane = tid & 63;
  #pragma unroll
  for (int q = 0; q < R3; ++q) {
    float mq = m[q], sq = sum[q];
    #pragma unroll
    for (int off = 32; off >= 1; off >>= 1) {
      float mo = __shfl_xor(mq, off);
      float so = __shfl_xor(sq, off);
      float mn = fmaxf(mq, mo);
      sq = sq * __expf(mq - mn) + so * __expf(mo - mn);
      mq = mn;
    }
    if (lane == 0) { sMS[wave][q][0] = mq; sMS[wave][q][1] = sq; }
  }
  __syncthreads();
  if (tid < R3) {
    float mq = sMS[0][tid][0], sq = sMS[0][tid][1];
    #pragma unroll
    for (int wv = 1; wv < NW3; ++wv) {
      float mo = sMS[wv][tid][0], so = sMS[wv][tid][1];
      float mn = fmaxf(mq, mo);
      sq = sq * __expf(mq - mn) + so * __expf(mo - mn);
      mq = mn;
    }
    sZ[tid] = mq + __logf(sq);
  }
  __syncthreads();

  // ---- pass B: recompute + write ----
  for (int c = 0; c < CH; ++c) {
    int v = c * (NT3 * 4) + tid * 4;
    float4 w[16];
    #pragma unroll
    for (int k = 0; k < 16; ++k) w[k] = *(const float4*)(Wout + k * V + v);
    float4 bb = *(const float4*)(bout + v);
    #pragma unroll
    for (int q = 0; q < R3; ++q) {
      const float4* th4 = (const float4*)(sTH + q * 16);
      float4 t0 = th4[0], t1 = th4[1], t2 = th4[2], t3 = th4[3];
      float th[16] = {t0.x,t0.y,t0.z,t0.w, t1.x,t1.y,t1.z,t1.w,
                      t2.x,t2.y,t2.z,t2.w, t3.x,t3.y,t3.z,t3.w};
      float lx = bb.x, ly = bb.y, lz = bb.z, lw = bb.w;
      #pragma unroll
      for (int k = 0; k < 16; ++k) {
        lx += th[k] * w[k].x; ly += th[k] * w[k].y;
        lz += th[k] * w[k].z; lw += th[k] * w[k].w;
      }
      float Z = sZ[q];
      float4 o4;
      o4.x = lx - Z; o4.y = ly - Z; o4.z = lz - Z; o4.w = lw - Z;
      *(float4*)(out + (long)(r0 + q) * V + v) = o4;
    }
  }
}

extern "C" void kernel_launch(void* const* d_in, const int* in_sizes, int n_in,
                              void* d_out, int out_size, void* d_ws, size_t ws_size,
                              hipStream_t stream) {
  (void)in_sizes; (void)n_in; (void)out_size; (void)ws_size;
  P1 p;
  p.x   = (const int*)  d_in[0];
  p.emb = (const float*)d_in[1];
  p.Wf1 = (const float*)d_in[2];  p.bf1 = (const float*)d_in[3];
  p.Wi1 = (const float*)d_in[4];  p.bi1 = (const float*)d_in[5];
  p.WC1 = (const float*)d_in[6];  p.bC1 = (const float*)d_in[7];
  p.Wo1 = (const float*)d_in[8];  p.bo1 = (const float*)d_in[9];
  p.Wf2 = (const float*)d_in[10]; p.bf2 = (const float*)d_in[11];
  p.Wi2 = (const float*)d_in[12]; p.bi2 = (const float*)d_in[13];
  p.WC2 = (const float*)d_in[14]; p.bC2 = (const float*)d_in[15];
  p.Wo2 = (const float*)d_in[16]; p.bo2 = (const float*)d_in[17];
  const float* Wout = (const float*)d_in[18];
  const float* bout = (const float*)d_in[19];

  float* pe   = (float*)d_ws;          // 2*11*TB floats = 180224
  float* hcat = pe + 2 * 11 * TB;      // TB*16 floats  = 131072
  float* out  = (float*)d_out;

  k_embed<<<dim3(TB / 256), dim3(256), 0, stream>>>(p, pe);
  k_lstm <<<dim3(2),        dim3(64),  0, stream>>>(p, pe, hcat);
  k_out  <<<dim3(TB / R3),  dim3(NT3), 0, stream>>>(hcat, Wout, bout, out);
}